// Round 8
// baseline (18.109 us; speedup 1.0000x reference)
//
#include <hip/hip_runtime.h>

namespace {
constexpr int kB = 16;
constexpr int kG = 16384;
constexpr int kC = 8;
constexpr int kS = 8;
constexpr int kLogG = 14;     // G = 2^14
constexpr int kChunks = 64;   // cg-space chunks
constexpr int kCGPerChunk = (kC * kG) / kChunks;  // 2048
constexpr int kThreads = 1024;
constexpr int kGroups = kThreads / 4;             // 256 cg lane-groups
constexpr int kIters = kCGPerChunk / kGroups;     // 8
}

typedef _Float16 h4 __attribute__((ext_vector_type(4)));

// quad_perm DPP move (VALU — keeps the cross-lane reduce off the LDS pipe)
template <int CTRL>
__device__ __forceinline__ float qperm(float x) {
    int r = __builtin_amdgcn_update_dpp(0, __builtin_bit_cast(int, x),
                                        CTRL, 0xF, 0xF, true);
    return __builtin_bit_cast(float, r);
}

// ---- pre-pass: xh[part][g] = fp16x4 of x[4*part .. 4*part+3][g]  (512 KB)
__global__ void build_xh(const float* __restrict__ x, h4* __restrict__ xh) {
    const int g = blockIdx.x * blockDim.x + threadIdx.x;
    if (g >= kG) return;
#pragma unroll
    for (int p = 0; p < 4; ++p) {
        h4 v;
#pragma unroll
        for (int j = 0; j < 4; ++j) v[j] = (_Float16)x[(p * 4 + j) * kG + g];
        xh[p * kG + g] = v;
    }
}

// Block = (chunk, part). LDS holds the part's (G, 4-batch) fp16 slice, staged
// via async global_load_lds (linear 128 KB copy, no VGPR round-trip, no cvt).
// 4-lane groups share one cg: lane sq handles s = {sq, sq+4}.
__global__ __launch_bounds__(kThreads) void clause_eval_lds(
        const h4* __restrict__ xh, const int* __restrict__ idx,
        float* __restrict__ out) {
    extern __shared__ h4 xs[];   // kG * 8 B = 128 KiB

    // bid -> (chunk, part): the 4 part-siblings of a chunk share an XCD
    const int bid = blockIdx.x;
    const int xcd = bid & 7;
    const int slot = bid >> 3;          // 0..31
    const int part = slot & 3;
    const int chunk = (slot >> 2) * 8 + xcd;   // 0..63

    const int t = threadIdx.x;
    const int sq = t & 3;            // s-quarter: handles s = sq, sq+4
    const int gid = t >> 2;          // 0..255 (cg lane-group)
    const int cgbase = chunk * kCGPerChunk;
    const int4* ibase = (const int4*)idx;      // 8 int4 per cg

    // ---- depth-4 upfront I-prefetch (32 VGPRs, statically indexed)
    const size_t ib0 = (size_t)(cgbase + gid) * kS;
    int4 pa[4], pb[4];
#pragma unroll
    for (int j = 0; j < 4; ++j) {
        pa[j] = ibase[ib0 + (size_t)j * kGroups * kS + sq];
        pb[j] = ibase[ib0 + (size_t)j * kGroups * kS + sq + 4];
    }

    // ---- async staging: xh part-slice -> LDS, 16 B/lane linear copy.
    // Wave-uniform LDS base + lane*16 (m104 contract); per-lane global src.
    {
        const int wave = t >> 6, lane = t & 63;
        const char* gsrc = (const char*)(xh + (size_t)part * kG);
#pragma unroll
        for (int i = 0; i < 8; ++i) {   // 16 waves * 8 * 1 KiB = 128 KiB
            const int off = wave * 8192 + i * 1024;
            __builtin_amdgcn_global_load_lds(
                (const __attribute__((address_space(1))) void*)(gsrc + off + lane * 16),
                (__attribute__((address_space(3))) void*)((char*)xs + off),
                16, 0, 0);
        }
    }
    __syncthreads();   // drains vmcnt (staging + prefetch) + barrier

    // hoisted output addressing (R5 mapping: cg = cgbase + j*kGroups + gid)
    const int c = chunk >> 3;
    float* ob = out + c * (kB * kG) + (part * 4 + sq) * kG
                    + ((chunk & 7) * kCGPerChunk + gid);

#pragma unroll
    for (int j = 0; j < kIters; ++j) {
        const int4 b0 = pa[j & 3], b1 = pb[j & 3];
        if (j + 4 < kIters) {   // refill slot (static index under full unroll)
            const size_t ibn = ib0 + (size_t)(j + 4) * kGroups * kS;
            pa[j & 3] = ibase[ibn + sq];
            pb[j & 3] = ibase[ibn + sq + 4];
        }

        // clause-body products for 4 b's (ds_read_b64 per index)
        h4 q = xs[b0.x] * xs[b0.y] * xs[b0.z] * xs[b0.w]
             + xs[b1.x] * xs[b1.y] * xs[b1.z] * xs[b1.w];
        float4 v = make_float4((float)q[0], (float)q[1], (float)q[2], (float)q[3]);

        // 4x4 transpose-reduce across the 4-lane group (pure VALU, DPP)
        const bool hi2 = (sq & 2) != 0;
        float c0 = (hi2 ? v.z : v.x) + qperm<0x4E>(hi2 ? v.x : v.z);  // xor 2
        float c1 = (hi2 ? v.w : v.y) + qperm<0x4E>(hi2 ? v.y : v.w);
        const bool odd = (sq & 1) != 0;
        float r = (odd ? c1 : c0) + qperm<0xB1>(odd ? c0 : c1);       // xor 1

        ob[j * kGroups] = r;
    }
}

// ---- fallback (fused staging, R5 form) if ws is too small ----
__global__ __launch_bounds__(kThreads) void clause_eval_fused(
        const float* __restrict__ x, const int* __restrict__ idx,
        float* __restrict__ out) {
    extern __shared__ h4 xs[];
    const int bid = blockIdx.x;
    const int xcd = bid & 7;
    const int slot = bid >> 3;
    const int part = slot & 3;
    const int chunk = (slot >> 2) * 8 + xcd;
    const int t = threadIdx.x;
    const int sq = t & 3;
    const int gid = t >> 2;
    const int cgbase = chunk * kCGPerChunk;
    const int4* ibase = (const int4*)idx;

    const size_t ib0 = (size_t)(cgbase + gid) * kS;
    int4 ca0 = ibase[ib0 + sq];
    int4 ca1 = ibase[ib0 + sq + 4];
    int4 na0 = ibase[ib0 + (size_t)kGroups * kS + sq];
    int4 na1 = ibase[ib0 + (size_t)kGroups * kS + sq + 4];

#pragma unroll
    for (int pass = 0; pass < kG / (kThreads * 4); ++pass) {
        const int g0 = (pass * kThreads + t) * 4;
        const float4 r0 = *(const float4*)(x + (part * 4 + 0) * kG + g0);
        const float4 r1 = *(const float4*)(x + (part * 4 + 1) * kG + g0);
        const float4 r2 = *(const float4*)(x + (part * 4 + 2) * kG + g0);
        const float4 r3 = *(const float4*)(x + (part * 4 + 3) * kG + g0);
        union { h4 h[2]; float4 f; } p0, p1;
        p0.h[0] = h4{(_Float16)r0.x, (_Float16)r1.x, (_Float16)r2.x, (_Float16)r3.x};
        p0.h[1] = h4{(_Float16)r0.y, (_Float16)r1.y, (_Float16)r2.y, (_Float16)r3.y};
        p1.h[0] = h4{(_Float16)r0.z, (_Float16)r1.z, (_Float16)r2.z, (_Float16)r3.z};
        p1.h[1] = h4{(_Float16)r0.w, (_Float16)r1.w, (_Float16)r2.w, (_Float16)r3.w};
        float4* dst = (float4*)(xs + g0);
        dst[0] = p0.f;
        dst[1] = p1.f;
    }
    __syncthreads();

    const int c = chunk >> 3;
    float* ob = out + c * (kB * kG) + (part * 4 + sq) * kG
                    + ((chunk & 7) * kCGPerChunk + gid);
#pragma unroll
    for (int j = 0; j < kIters; ++j) {
        const int4 b0 = ca0, b1 = ca1;
        ca0 = na0; ca1 = na1;
        if (j + 2 < kIters) {
            const size_t ibn = ib0 + (size_t)(j + 2) * kGroups * kS;
            na0 = ibase[ibn + sq];
            na1 = ibase[ibn + sq + 4];
        }
        h4 q = xs[b0.x] * xs[b0.y] * xs[b0.z] * xs[b0.w]
             + xs[b1.x] * xs[b1.y] * xs[b1.z] * xs[b1.w];
        float4 v = make_float4((float)q[0], (float)q[1], (float)q[2], (float)q[3]);
        const bool hi2 = (sq & 2) != 0;
        float c0 = (hi2 ? v.z : v.x) + qperm<0x4E>(hi2 ? v.x : v.z);
        float c1 = (hi2 ? v.w : v.y) + qperm<0x4E>(hi2 ? v.y : v.w);
        const bool odd = (sq & 1) != 0;
        float r = (odd ? c1 : c0) + qperm<0xB1>(odd ? c0 : c1);
        ob[j * kGroups] = r;
    }
}

extern "C" void kernel_launch(void* const* d_in, const int* in_sizes, int n_in,
                              void* d_out, int out_size, void* d_ws, size_t ws_size,
                              hipStream_t stream) {
    const float* x = (const float*)d_in[0];
    const int* I = (const int*)d_in[1];
    float* out = (float*)d_out;

    const int grid = kChunks * 4;                // 256 blocks -> 1/CU
    const size_t lds = (size_t)kG * sizeof(h4);  // 128 KiB dynamic
    const size_t xh_bytes = (size_t)4 * kG * sizeof(h4);  // 512 KiB

    if (ws_size >= xh_bytes) {
        h4* xh = (h4*)d_ws;
        build_xh<<<kG / 256, 256, 0, stream>>>(x, xh);
        clause_eval_lds<<<grid, kThreads, lds, stream>>>(xh, I, out);
    } else {
        clause_eval_fused<<<grid, kThreads, lds, stream>>>(x, I, out);
    }
}

// Round 9
// 13.255 us; speedup vs baseline: 1.3662x; 1.3662x over previous
//
#include <hip/hip_runtime.h>

namespace {
constexpr int kB = 16;
constexpr int kG = 16384;
constexpr int kC = 8;
constexpr int kS = 8;
constexpr int kLogG = 14;     // G = 2^14
constexpr int kChunks = 64;   // cg-space chunks
constexpr int kCGPerChunk = (kC * kG) / kChunks;  // 2048
constexpr int kThreads = 1024;
constexpr int kGroups = kThreads / 4;             // 256 cg lane-groups
constexpr int kIters = kCGPerChunk / kGroups;     // 8
}

typedef _Float16 h4 __attribute__((ext_vector_type(4)));
typedef float f4v __attribute__((ext_vector_type(4)));

// quad_perm DPP move (VALU — keeps the cross-lane reduce off the LDS pipe)
template <int CTRL>
__device__ __forceinline__ float qperm(float x) {
    int r = __builtin_amdgcn_update_dpp(0, __builtin_bit_cast(int, x),
                                        CTRL, 0xF, 0xF, true);
    return __builtin_bit_cast(float, r);
}

// Block = (chunk, part). LDS holds the part's full (G, 4-batch) fp16 slice.
// 4-lane groups share one cg: lane sq handles s = {sq, sq+4}.
// cg = cg0 + j (consecutive per thread) -> 8 outputs = 2 b128 nt stores.
__global__ __launch_bounds__(kThreads) void clause_eval_lds(
        const float* __restrict__ x, const int* __restrict__ idx,
        float* __restrict__ out) {
    extern __shared__ h4 xs[];   // kG * 8 B = 128 KiB

    // bid -> (chunk, part): the 4 part-siblings of a chunk share an XCD (L2 reuse of I)
    const int bid = blockIdx.x;
    const int xcd = bid & 7;
    const int slot = bid >> 3;          // 0..31
    const int part = slot & 3;
    const int chunk = (slot >> 2) * 8 + xcd;   // 0..63

    const int t = threadIdx.x;
    const int sq = t & 3;            // s-quarter: handles s = sq, sq+4
    const int gid = t >> 2;          // 0..255 (cg lane-group)
    const int cg0 = chunk * kCGPerChunk + gid * kIters;
    const int4* ibase = (const int4*)idx;      // 8 int4 per cg

    // ---- depth-2 rotating I-prefetch, issued BEFORE staging (R5 structure)
    const size_t ib0 = (size_t)cg0 * kS;
    int4 ca0 = ibase[ib0 + sq];
    int4 ca1 = ibase[ib0 + sq + 4];
    int4 na0 = ibase[ib0 + kS + sq];
    int4 na1 = ibase[ib0 + kS + sq + 4];

    // ---- fused staging: x rows [4p..4p+3] -> LDS as fp16x4 per g ----
#pragma unroll
    for (int pass = 0; pass < kG / (kThreads * 4); ++pass) {   // 4 passes
        const int g0 = (pass * kThreads + t) * 4;
        const float4 r0 = *(const float4*)(x + (part * 4 + 0) * kG + g0);
        const float4 r1 = *(const float4*)(x + (part * 4 + 1) * kG + g0);
        const float4 r2 = *(const float4*)(x + (part * 4 + 2) * kG + g0);
        const float4 r3 = *(const float4*)(x + (part * 4 + 3) * kG + g0);
        union { h4 h[2]; float4 f; } p0, p1;
        p0.h[0] = h4{(_Float16)r0.x, (_Float16)r1.x, (_Float16)r2.x, (_Float16)r3.x};
        p0.h[1] = h4{(_Float16)r0.y, (_Float16)r1.y, (_Float16)r2.y, (_Float16)r3.y};
        p1.h[0] = h4{(_Float16)r0.z, (_Float16)r1.z, (_Float16)r2.z, (_Float16)r3.z};
        p1.h[1] = h4{(_Float16)r0.w, (_Float16)r1.w, (_Float16)r2.w, (_Float16)r3.w};
        float4* dst = (float4*)(xs + g0);
        dst[0] = p0.f;      // ds_write_b128 x2, contiguous
        dst[1] = p1.f;
    }
    __syncthreads();

    __builtin_amdgcn_s_setprio(1);
    float rbuf[kIters];
#pragma unroll
    for (int j = 0; j < kIters; ++j) {
        const int4 b0 = ca0, b1 = ca1;
        ca0 = na0; ca1 = na1;
        if (j + 2 < kIters) {   // refill (static under full unroll, no spill)
            const size_t ibn = ib0 + (size_t)(j + 2) * kS;
            na0 = ibase[ibn + sq];
            na1 = ibase[ibn + sq + 4];
        }

        // clause-body products for 4 b's (ds_read_b64 per index)
        h4 q = xs[b0.x] * xs[b0.y] * xs[b0.z] * xs[b0.w]
             + xs[b1.x] * xs[b1.y] * xs[b1.z] * xs[b1.w];
        float4 v = make_float4((float)q[0], (float)q[1], (float)q[2], (float)q[3]);

        // 4x4 transpose-reduce across the 4-lane group (pure VALU, DPP)
        const bool hi2 = (sq & 2) != 0;
        float c0 = (hi2 ? v.z : v.x) + qperm<0x4E>(hi2 ? v.x : v.z);  // xor 2
        float c1 = (hi2 ? v.w : v.y) + qperm<0x4E>(hi2 ? v.y : v.w);
        const bool odd = (sq & 1) != 0;
        rbuf[j] = (odd ? c1 : c0) + qperm<0xB1>(odd ? c0 : c1);       // xor 1
    }
    __builtin_amdgcn_s_setprio(0);

    // ---- epilogue: 8 consecutive g -> 2 b128 NONTEMPORAL stores.
    // nt keeps the 8 MB dead output from evicting I/x lines that the
    // part-sibling blocks on this XCD still reuse in L2.
    const int c = chunk >> 3;
    const int gbase = (chunk & 7) * kCGPerChunk + gid * kIters;
    float* ob = out + c * (kB * kG) + (part * 4 + sq) * kG + gbase;
    f4v o0 = {rbuf[0], rbuf[1], rbuf[2], rbuf[3]};
    f4v o1 = {rbuf[4], rbuf[5], rbuf[6], rbuf[7]};
    __builtin_nontemporal_store(o0, (f4v*)ob);
    __builtin_nontemporal_store(o1, (f4v*)(ob + 4));
}

extern "C" void kernel_launch(void* const* d_in, const int* in_sizes, int n_in,
                              void* d_out, int out_size, void* d_ws, size_t ws_size,
                              hipStream_t stream) {
    const float* x = (const float*)d_in[0];
    const int* I = (const int*)d_in[1];
    float* out = (float*)d_out;

    const int grid = kChunks * 4;                // 256 blocks -> 1/CU
    const size_t lds = (size_t)kG * sizeof(h4);  // 128 KiB dynamic
    clause_eval_lds<<<grid, kThreads, lds, stream>>>(x, I, out);
}